// Round 11
// baseline (297.255 us; speedup 1.0000x reference)
//
#include <hip/hip_runtime.h>
#include <hip/hip_fp16.h>

#define DMODEL 192
#define DINNER 384
#define NPOS   4096   // B*H*W = 4*32*32
#define SEQL   1024   // H*W
#define DSTATE 16
#define DTRANK 12

__device__ __forceinline__ float silu_f(float v) { return v * (1.f / (1.f + __expf(-v))); }

__device__ __forceinline__ int scan_pos(int dir, int l) {
    int s = (dir & 1) ? (SEQL - 1 - l) : l;
    return (dir & 2) ? (((s & 31) << 5) | (s >> 5)) : s;
}

// ---------------------------------------------------------------------------
// K1: xz = x @ W_in, both halves. x_val fp32 + gz = silu(z).
//     512 blocks x 384 thr, 8 positions/block.
// ---------------------------------------------------------------------------
__global__ void k1_inproj8(const float* __restrict__ x, const float* __restrict__ W_in,
                           float* __restrict__ x_val, float* __restrict__ gz) {
    __shared__ float xs[8 * DMODEL];
    const int t = threadIdx.x;
    const int pos0 = blockIdx.x << 3;
    for (int i = t; i < 8 * DMODEL; i += 384) xs[i] = x[pos0 * DMODEL + i];
    __syncthreads();

    float a0[8] = {0,0,0,0,0,0,0,0};
    float a1[8] = {0,0,0,0,0,0,0,0};
    for (int c = 0; c < DMODEL; ++c) {
        float w0 = W_in[c * 768 + t];
        float w1 = W_in[c * 768 + 384 + t];
#pragma unroll
        for (int g = 0; g < 8; ++g) {
            float xv = xs[g * DMODEL + c];
            a0[g] += w0 * xv;
            a1[g] += w1 * xv;
        }
    }
#pragma unroll
    for (int g = 0; g < 8; ++g) {
        x_val[(pos0 + g) * DINNER + t] = a0[g];
        gz[(pos0 + g) * DINNER + t]    = silu_f(a1[g]);
    }
}

// ---------------------------------------------------------------------------
// K2: depthwise conv3x3 + bias + silu -> u (fp16) ; xd = u @ W_x (44 cols) ;
//     dt = softplus(b_dt + xd[:12] @ W_dt) ; y_acc init = 4*D*u.
//     (k2c fused in — xd is already in LDS.) 4096 blocks x 384 thr.
// ---------------------------------------------------------------------------
__global__ void k2_conv_dt(const float* __restrict__ x_val,
                           const float* __restrict__ conv_w, const float* __restrict__ conv_b,
                           const float* __restrict__ W_x, const float* __restrict__ W_dt,
                           const float* __restrict__ b_dt, const float* __restrict__ Dp,
                           __half* __restrict__ u_out, float* __restrict__ xd_out,
                           float* __restrict__ dt32, float* __restrict__ y_acc) {
    __shared__ float us[DINNER];
    __shared__ float part[8 * 44];
    __shared__ float xdl[44];
    const int t = threadIdx.x;
    const int pos = blockIdx.x;
    const int b = pos >> 10, hw = pos & 1023, h = hw >> 5, w = hw & 31;

    float acc = conv_b[t];
#pragma unroll
    for (int i = 0; i < 3; ++i) {
        int hh = h + i - 1;
        if (hh < 0 || hh > 31) continue;
#pragma unroll
        for (int j = 0; j < 3; ++j) {
            int ww = w + j - 1;
            if (ww < 0 || ww > 31) continue;
            acc += x_val[((b * 32 + hh) * 32 + ww) * DINNER + t] * conv_w[t * 9 + i * 3 + j];
        }
    }
    float uv = silu_f(acc);
    us[t] = uv;
    u_out[pos * DINNER + t] = __float2half(uv);
    __syncthreads();

    if (t < 352) {
        int o = t % 44, p = t / 44;
        float s = 0.f;
        int j0 = p * 48;
        for (int j = j0; j < j0 + 48; ++j) s += us[j] * W_x[j * 44 + o];
        part[p * 44 + o] = s;
    }
    __syncthreads();
    if (t < 44) {
        float s = 0.f;
#pragma unroll
        for (int p = 0; p < 8; ++p) s += part[p * 44 + t];
        xd_out[pos * 48 + t] = s;
        xdl[t] = s;
    }
    __syncthreads();

    float raw = b_dt[t];
#pragma unroll
    for (int r = 0; r < DTRANK; ++r) raw += xdl[r] * W_dt[r * DINNER + t];
    dt32[pos * DINNER + t] = fmaxf(raw, 0.f) + log1pf(__expf(-fabsf(raw)));

    y_acc[pos * DINNER + t] = 4.f * Dp[t] * uv;
}

// ---------------------------------------------------------------------------
// K3: lane-per-channel scan. One lane owns all 16 states of one d.
//     - no cross-lane shuffles in the hot loop (n-sum is in registers)
//     - wave-uniform alive-count nAmax = 105 / min_wave(cumdt): deaths are
//       ordered in n (cum_n ~ -(n+1)*cumdt); threshold 105 > 103.3 denormal
//       death line, so live n are never skipped and skipped n are exact 0.
//     96 blocks x 64 thr : (dir,b) x 6 d-groups of 64.
// ---------------------------------------------------------------------------
__global__ void k3_lane(const __half* __restrict__ u, const float* __restrict__ xd,
                        const float* __restrict__ dt32, const float* __restrict__ A_log,
                        float* __restrict__ y_acc) {
    const int lane = threadIdx.x;            // 0..63
    const int bi = blockIdx.x;               // 96 = 16 db * 6 dgroup
    const int dgroup = bi % 6;
    const int db = bi / 6;
    const int b = db & 3, dir = db >> 2;
    const int d = dgroup * 64 + lane;

    float A[DSTATE];
#pragma unroll
    for (int n = 0; n < DSTATE; ++n) A[n] = -__expf(A_log[d * DSTATE + n]);

    const __half* ub  = u    + b * SEQL * DINNER;
    const float*  xb  = xd   + b * SEQL * 48;
    const float*  dtb = dt32 + b * SEQL * DINNER;
    float* yb = y_acc + b * SEQL * DINNER;

    float cum[DSTATE], S[DSTATE];
#pragma unroll
    for (int n = 0; n < DSTATE; ++n) { cum[n] = 0.f; S[n] = 0.f; }
    float cumdt = 0.f;
    int nAmax = DSTATE;

    for (int l0 = 0; l0 < SEQL; l0 += 8) {
        float dtv[8], uv[8];
        int pk[8];
#pragma unroll
        for (int k = 0; k < 8; ++k) {
            int pos = scan_pos(dir, l0 + k);
            pk[k]  = pos;
            dtv[k] = dtb[pos * DINNER + d];
            uv[k]  = __half2float(ub[pos * DINNER + d]);
        }
#pragma unroll
        for (int k = 0; k < 8; ++k) {
            const float* xr = xb + pk[k] * 48;
            float wdu = dtv[k] * uv[k];
            float csum = 0.f;
#pragma unroll
            for (int n = 0; n < DSTATE; ++n) {
                if (n < nAmax) {                      // wave-uniform branch
                    cum[n] += dtv[k] * A[n];
                    float decay = __expf(cum[n]);     // underflow semantics preserved
                    float Bn = xr[DTRANK + n];        // wave-uniform address
                    float Cn = xr[DTRANK + DSTATE + n];
                    S[n] += (wdu * Bn) * __builtin_amdgcn_rcpf(decay + 1e-12f);
                    csum += decay * S[n] * Cn;
                }
            }
            cumdt += dtv[k];
            atomicAdd(&yb[pk[k] * DINNER + d], csum);
        }
        // wave-uniform alive-count refresh (conservative: min cumdt over wave)
        float cmin = cumdt;
#pragma unroll
        for (int off = 32; off > 0; off >>= 1) cmin = fminf(cmin, __shfl_xor(cmin, off));
        int na = (cmin > 6.5625f) ? (int)(105.f / cmin) : DSTATE;
        if (na > DSTATE) na = DSTATE;
        nAmax = __builtin_amdgcn_readfirstlane(na);
        if (nAmax <= 0) break;                        // all states dead: rest is exact 0
    }
}

// ---------------------------------------------------------------------------
// K4: LayerNorm + gate by stored gz + out-proj. 1024 blocks x 192 thr,
//     4 positions/block (amortizes W_out L2 reads).
// ---------------------------------------------------------------------------
__global__ void k4_out4(const float* __restrict__ y_acc, const float* __restrict__ gz,
                        const float* __restrict__ gamma, const float* __restrict__ beta,
                        const float* __restrict__ W_out, float* __restrict__ out) {
    __shared__ float g_s[4 * DINNER];
    __shared__ float red[6];
    const int t = threadIdx.x;          // 0..191
    const int lane = t & 63, wave = t >> 6;
    const int pos0 = blockIdx.x << 2;

    const float g0c = gamma[t], g1c = gamma[t + 192];
    const float b0c = beta[t],  b1c = beta[t + 192];

    for (int p = 0; p < 4; ++p) {
        int pos = pos0 + p;
        float y0 = y_acc[pos * DINNER + t];
        float y1 = y_acc[pos * DINNER + t + 192];

        float s = y0 + y1;
#pragma unroll
        for (int off = 32; off > 0; off >>= 1) s += __shfl_xor(s, off);
        if (lane == 0) red[wave] = s;
        __syncthreads();
        float mu = (red[0] + red[1] + red[2]) * (1.f / 384.f);

        float d0 = y0 - mu, d1 = y1 - mu;
        float sq = d0 * d0 + d1 * d1;
#pragma unroll
        for (int off = 32; off > 0; off >>= 1) sq += __shfl_xor(sq, off);
        if (lane == 0) red[3 + wave] = sq;
        __syncthreads();
        float var = (red[3] + red[4] + red[5]) * (1.f / 384.f);
        float inv = rsqrtf(var + 1e-5f);

        g_s[p * DINNER + t]       = (d0 * inv * g0c + b0c) * gz[pos * DINNER + t];
        g_s[p * DINNER + t + 192] = (d1 * inv * g1c + b1c) * gz[pos * DINNER + t + 192];
        __syncthreads();
    }

    float acc[4] = {0.f, 0.f, 0.f, 0.f};
    for (int dd = 0; dd < DINNER; ++dd) {
        float w = W_out[dd * DMODEL + t];
#pragma unroll
        for (int p = 0; p < 4; ++p) acc[p] += g_s[p * DINNER + dd] * w;
    }
#pragma unroll
    for (int p = 0; p < 4; ++p) out[(pos0 + p) * DMODEL + t] = acc[p];
}

// ---------------------------------------------------------------------------
extern "C" void kernel_launch(void* const* d_in, const int* in_sizes, int n_in,
                              void* d_out, int out_size, void* d_ws, size_t ws_size,
                              hipStream_t stream) {
    (void)in_sizes; (void)n_in; (void)out_size; (void)ws_size;
    const float* x      = (const float*)d_in[0];
    const float* W_in   = (const float*)d_in[1];
    const float* conv_w = (const float*)d_in[2];
    const float* conv_b = (const float*)d_in[3];
    const float* W_x    = (const float*)d_in[4];
    const float* W_dt   = (const float*)d_in[5];
    const float* b_dt   = (const float*)d_in[6];
    const float* A_log  = (const float*)d_in[7];
    const float* Dp     = (const float*)d_in[8];
    const float* W_out  = (const float*)d_in[9];
    const float* gamma  = (const float*)d_in[10];
    const float* beta   = (const float*)d_in[11];

    // ws layout (22.75 MB; >=27.75 MB verified available):
    //  R1   x_val fp32 (k1->k2) -> y_acc (k2->k4) : 6 MB    @ 0
    //  u    fp16                                  : 3 MB    @ 6291456
    //  xd   fp32 4096x48                          : 0.75 MB @ 9437184
    //  dt32 fp32                                  : 6 MB    @ 10223616
    //  gz   fp32                                  : 6 MB    @ 16515072
    char* base = (char*)d_ws;
    float*  R1   = (float*)base;
    __half* u    = (__half*)(base + 6291456);
    float*  xd   = (float*)(base + 9437184);
    float*  dt32 = (float*)(base + 10223616);
    float*  gz   = (float*)(base + 16515072);

    hipLaunchKernelGGL(k1_inproj8, dim3(NPOS / 8), dim3(384), 0, stream, x, W_in, R1, gz);
    hipLaunchKernelGGL(k2_conv_dt, dim3(NPOS), dim3(384), 0, stream,
                       R1, conv_w, conv_b, W_x, W_dt, b_dt, Dp, u, xd, dt32, R1);
    hipLaunchKernelGGL(k3_lane, dim3(96), dim3(64), 0, stream,
                       u, xd, dt32, A_log, R1);
    hipLaunchKernelGGL(k4_out4, dim3(NPOS / 4), dim3(192), 0, stream,
                       R1, gz, gamma, beta, W_out, (float*)d_out);
}

// Round 13
// 225.685 us; speedup vs baseline: 1.3171x; 1.3171x over previous
//
#include <hip/hip_runtime.h>
#include <hip/hip_fp16.h>

#define DMODEL 192
#define DINNER 384
#define NPOS   4096   // B*H*W = 4*32*32
#define SEQL   1024   // H*W
#define DSTATE 16
#define DTRANK 12

__device__ __forceinline__ float silu_f(float v) { return v * (1.f / (1.f + __expf(-v))); }

__device__ __forceinline__ int scan_pos(int dir, int l) {
    int s = (dir & 1) ? (SEQL - 1 - l) : l;
    return (dir & 2) ? (((s & 31) << 5) | (s >> 5)) : s;
}

// ---------------------------------------------------------------------------
// K1: xz = x @ W_in, both halves. x_val fp32 + gz = silu(z).
//     512 blocks x 384 thr, 8 positions/block.
// ---------------------------------------------------------------------------
__global__ void k1_inproj8(const float* __restrict__ x, const float* __restrict__ W_in,
                           float* __restrict__ x_val, float* __restrict__ gz) {
    __shared__ float xs[8 * DMODEL];
    const int t = threadIdx.x;
    const int pos0 = blockIdx.x << 3;
    for (int i = t; i < 8 * DMODEL; i += 384) xs[i] = x[pos0 * DMODEL + i];
    __syncthreads();

    float a0[8] = {0,0,0,0,0,0,0,0};
    float a1[8] = {0,0,0,0,0,0,0,0};
    for (int c = 0; c < DMODEL; ++c) {
        float w0 = W_in[c * 768 + t];
        float w1 = W_in[c * 768 + 384 + t];
#pragma unroll
        for (int g = 0; g < 8; ++g) {
            float xv = xs[g * DMODEL + c];
            a0[g] += w0 * xv;
            a1[g] += w1 * xv;
        }
    }
#pragma unroll
    for (int g = 0; g < 8; ++g) {
        x_val[(pos0 + g) * DINNER + t] = a0[g];
        gz[(pos0 + g) * DINNER + t]    = silu_f(a1[g]);
    }
}

// ---------------------------------------------------------------------------
// K2: depthwise conv3x3 + bias + silu -> u (fp16) ; xd = u @ W_x (44 cols) ;
//     dt = softplus(b_dt + xd[:12] @ W_dt) ; y_acc init = 4*D*u.
//     y_acc is a SEPARATE buffer from x_val (cross-block halo reads of x_val
//     must never race with y_init writes — round-12 bug).
// ---------------------------------------------------------------------------
__global__ void k2_conv_dt(const float* __restrict__ x_val,
                           const float* __restrict__ conv_w, const float* __restrict__ conv_b,
                           const float* __restrict__ W_x, const float* __restrict__ W_dt,
                           const float* __restrict__ b_dt, const float* __restrict__ Dp,
                           __half* __restrict__ u_out, float* __restrict__ xd_out,
                           float* __restrict__ dt32, float* __restrict__ y_acc) {
    __shared__ float us[DINNER];
    __shared__ float part[8 * 44];
    __shared__ float xdl[44];
    const int t = threadIdx.x;
    const int pos = blockIdx.x;
    const int b = pos >> 10, hw = pos & 1023, h = hw >> 5, w = hw & 31;

    float acc = conv_b[t];
#pragma unroll
    for (int i = 0; i < 3; ++i) {
        int hh = h + i - 1;
        if (hh < 0 || hh > 31) continue;
#pragma unroll
        for (int j = 0; j < 3; ++j) {
            int ww = w + j - 1;
            if (ww < 0 || ww > 31) continue;
            acc += x_val[((b * 32 + hh) * 32 + ww) * DINNER + t] * conv_w[t * 9 + i * 3 + j];
        }
    }
    float uv = silu_f(acc);
    us[t] = uv;
    u_out[pos * DINNER + t] = __float2half(uv);
    __syncthreads();

    if (t < 352) {
        int o = t % 44, p = t / 44;
        float s = 0.f;
        int j0 = p * 48;
        for (int j = j0; j < j0 + 48; ++j) s += us[j] * W_x[j * 44 + o];
        part[p * 44 + o] = s;
    }
    __syncthreads();
    if (t < 44) {
        float s = 0.f;
#pragma unroll
        for (int p = 0; p < 8; ++p) s += part[p * 44 + t];
        xd_out[pos * 48 + t] = s;
        xdl[t] = s;
    }
    __syncthreads();

    float raw = b_dt[t];
#pragma unroll
    for (int r = 0; r < DTRANK; ++r) raw += xdl[r] * W_dt[r * DINNER + t];
    dt32[pos * DINNER + t] = fmaxf(raw, 0.f) + log1pf(__expf(-fabsf(raw)));

    y_acc[pos * DINNER + t] = 4.f * Dp[t] * uv;   // separate buffer: race-free
}

// ---------------------------------------------------------------------------
// K3: thread=(d,n), 16-lane butterfly, ballot early exit, batched phases:
//     phase1 cum chain + 8 indep exps ; phase2 8 indep rcps ;
//     phase3 8-FMA serial S chain ; phase4 8 butterflies level-by-level ;
//     phase5 8 atomics. Arithmetic & reduction order identical to round 10.
//     384 blocks x 256 thr.
// ---------------------------------------------------------------------------
__global__ void k3_early(const __half* __restrict__ u, const float* __restrict__ xd,
                         const float* __restrict__ dt32, const float* __restrict__ A_log,
                         float* __restrict__ y_acc) {
    const int t = threadIdx.x;
    const int n = t & 15, dl = t >> 4;
    const int bi = blockIdx.x;
    const int chunk = bi % 24;
    const int b = (bi / 24) % 4;
    const int dir = bi / 96;
    const int d = chunk * 16 + dl;

    const float A = -__expf(A_log[d * DSTATE + n]);

    const __half* ub  = u    + b * SEQL * DINNER;
    const float* xb   = xd   + b * SEQL * 48;
    const float* dtb  = dt32 + b * SEQL * DINNER;
    float* yb = y_acc + b * SEQL * DINNER;

    float cum = 0.f, S = 0.f;
    for (int l0 = 0; l0 < SEQL; l0 += 8) {
        float dtv[8], Bv[8], Cv[8], uv[8];
        int   pk[8];
#pragma unroll
        for (int k = 0; k < 8; ++k) {
            int pos = scan_pos(dir, l0 + k);
            pk[k]  = pos;
            dtv[k] = dtb[pos * DINNER + d];
            Bv[k]  = xb[pos * 48 + DTRANK + n];
            Cv[k]  = xb[pos * 48 + DTRANK + DSTATE + n];
            uv[k]  = __half2float(ub[pos * DINNER + d]);
        }
        float decay[8];
#pragma unroll
        for (int k = 0; k < 8; ++k) { cum += dtv[k] * A; decay[k] = __expf(cum); }
        float rc[8];
#pragma unroll
        for (int k = 0; k < 8; ++k) rc[k] = __builtin_amdgcn_rcpf(decay[k] + 1e-12f);
        float c[8];
#pragma unroll
        for (int k = 0; k < 8; ++k) {
            S += (dtv[k] * Bv[k] * uv[k]) * rc[k];
            c[k] = decay[k] * S * Cv[k];
        }
#pragma unroll
        for (int off = 1; off <= 8; off <<= 1) {
#pragma unroll
            for (int k = 0; k < 8; ++k) c[k] += __shfl_xor(c[k], off);
        }
        if (n == 0) {
#pragma unroll
            for (int k = 0; k < 8; ++k) atomicAdd(&yb[pk[k] * DINNER + d], c[k]);
        }
        if (__ballot(cum > -110.f) == 0ull) break;   // all lanes dead -> rest exact 0
    }
}

// ---------------------------------------------------------------------------
// K4: LayerNorm + gate by stored gz + out-proj. 512 blocks x 192 thr,
//     8 positions/block (halves W_out L2 traffic vs 4-pos).
// ---------------------------------------------------------------------------
__global__ void k4_out8(const float* __restrict__ y_acc, const float* __restrict__ gz,
                        const float* __restrict__ gamma, const float* __restrict__ beta,
                        const float* __restrict__ W_out, float* __restrict__ out) {
    __shared__ float g_s[8 * DINNER];
    __shared__ float red[6];
    const int t = threadIdx.x;          // 0..191
    const int lane = t & 63, wave = t >> 6;
    const int pos0 = blockIdx.x << 3;

    const float g0c = gamma[t], g1c = gamma[t + 192];
    const float b0c = beta[t],  b1c = beta[t + 192];

    for (int p = 0; p < 8; ++p) {
        int pos = pos0 + p;
        float y0 = y_acc[pos * DINNER + t];
        float y1 = y_acc[pos * DINNER + t + 192];

        float s = y0 + y1;
#pragma unroll
        for (int off = 32; off > 0; off >>= 1) s += __shfl_xor(s, off);
        if (lane == 0) red[wave] = s;
        __syncthreads();
        float mu = (red[0] + red[1] + red[2]) * (1.f / 384.f);

        float d0 = y0 - mu, d1 = y1 - mu;
        float sq = d0 * d0 + d1 * d1;
#pragma unroll
        for (int off = 32; off > 0; off >>= 1) sq += __shfl_xor(sq, off);
        if (lane == 0) red[3 + wave] = sq;
        __syncthreads();
        float var = (red[3] + red[4] + red[5]) * (1.f / 384.f);
        float inv = rsqrtf(var + 1e-5f);

        g_s[p * DINNER + t]       = (d0 * inv * g0c + b0c) * gz[pos * DINNER + t];
        g_s[p * DINNER + t + 192] = (d1 * inv * g1c + b1c) * gz[pos * DINNER + t + 192];
        __syncthreads();
    }

    float acc[8] = {0,0,0,0,0,0,0,0};
    for (int dd = 0; dd < DINNER; ++dd) {
        float w = W_out[dd * DMODEL + t];
#pragma unroll
        for (int p = 0; p < 8; ++p) acc[p] += g_s[p * DINNER + dd] * w;
    }
#pragma unroll
    for (int p = 0; p < 8; ++p) out[(pos0 + p) * DMODEL + t] = acc[p];
}

// ---------------------------------------------------------------------------
extern "C" void kernel_launch(void* const* d_in, const int* in_sizes, int n_in,
                              void* d_out, int out_size, void* d_ws, size_t ws_size,
                              hipStream_t stream) {
    (void)in_sizes; (void)n_in; (void)out_size; (void)ws_size;
    const float* x      = (const float*)d_in[0];
    const float* W_in   = (const float*)d_in[1];
    const float* conv_w = (const float*)d_in[2];
    const float* conv_b = (const float*)d_in[3];
    const float* W_x    = (const float*)d_in[4];
    const float* W_dt   = (const float*)d_in[5];
    const float* b_dt   = (const float*)d_in[6];
    const float* A_log  = (const float*)d_in[7];
    const float* Dp     = (const float*)d_in[8];
    const float* W_out  = (const float*)d_in[9];
    const float* gamma  = (const float*)d_in[10];
    const float* beta   = (const float*)d_in[11];

    // ws layout (27.75 MB total = 29097984 B; exactly the size verified
    // available in round 9 where mode-2 ran):
    //  x_val fp32 : 6 MB    @ 0
    //  u     fp16 : 3 MB    @ 6291456
    //  xd    fp32 : 0.75 MB @ 9437184
    //  dt32  fp32 : 6 MB    @ 10223616
    //  gz    fp32 : 6 MB    @ 16515072
    //  y_acc fp32 : 6 MB    @ 22806528   (SEPARATE from x_val: no halo race)
    char* base = (char*)d_ws;
    float*  x_val = (float*)base;
    __half* u     = (__half*)(base + 6291456);
    float*  xd    = (float*)(base + 9437184);
    float*  dt32  = (float*)(base + 10223616);
    float*  gz    = (float*)(base + 16515072);
    float*  y_acc = (float*)(base + 22806528);

    hipLaunchKernelGGL(k1_inproj8, dim3(NPOS / 8), dim3(384), 0, stream, x, W_in, x_val, gz);
    hipLaunchKernelGGL(k2_conv_dt, dim3(NPOS), dim3(384), 0, stream,
                       x_val, conv_w, conv_b, W_x, W_dt, b_dt, Dp, u, xd, dt32, y_acc);
    hipLaunchKernelGGL(k3_early, dim3(384), dim3(256), 0, stream,
                       u, xd, dt32, A_log, y_acc);
    hipLaunchKernelGGL(k4_out8, dim3(NPOS / 8), dim3(192), 0, stream,
                       y_acc, gz, gamma, beta, W_out, (float*)d_out);
}

// Round 14
// 217.819 us; speedup vs baseline: 1.3647x; 1.0361x over previous
//
#include <hip/hip_runtime.h>
#include <hip/hip_fp16.h>

#define DMODEL 192
#define DINNER 384
#define NPOS   4096   // B*H*W = 4*32*32
#define SEQL   1024   // H*W
#define DSTATE 16
#define DTRANK 12

__device__ __forceinline__ float silu_f(float v) { return v * (1.f / (1.f + __expf(-v))); }

__device__ __forceinline__ int scan_pos(int dir, int l) {
    int s = (dir & 1) ? (SEQL - 1 - l) : l;
    return (dir & 2) ? (((s & 31) << 5) | (s >> 5)) : s;
}

// ---------------------------------------------------------------------------
// K1: xz = x @ W_in, both halves. 512 blocks x 768 thr — one output col per
//     thread, 8 positions per block. float4 LDS reads, 4x c-unroll.
// ---------------------------------------------------------------------------
__global__ void k1_inproj(const float* __restrict__ x, const float* __restrict__ W_in,
                          float* __restrict__ x_val, float* __restrict__ gz) {
    __shared__ float xs[8 * DMODEL];
    const int t = threadIdx.x;          // 0..767 = output col
    const int pos0 = blockIdx.x << 3;
    for (int i = t; i < 8 * DMODEL; i += 768) xs[i] = x[pos0 * DMODEL + i];
    __syncthreads();

    float acc[8] = {0,0,0,0,0,0,0,0};
    for (int c = 0; c < DMODEL; c += 4) {
        float w0 = W_in[(c + 0) * 768 + t];
        float w1 = W_in[(c + 1) * 768 + t];
        float w2 = W_in[(c + 2) * 768 + t];
        float w3 = W_in[(c + 3) * 768 + t];
#pragma unroll
        for (int g = 0; g < 8; ++g) {
            const float4 xv = *(const float4*)&xs[g * DMODEL + c];
            acc[g] += xv.x * w0 + xv.y * w1 + xv.z * w2 + xv.w * w3;
        }
    }
    if (t < DINNER) {
#pragma unroll
        for (int g = 0; g < 8; ++g) x_val[(pos0 + g) * DINNER + t] = acc[g];
    } else {
#pragma unroll
        for (int g = 0; g < 8; ++g) gz[(pos0 + g) * DINNER + (t - DINNER)] = silu_f(acc[g]);
    }
}

// ---------------------------------------------------------------------------
// K2: depthwise conv3x3 + bias + silu -> u (fp16) ; xd = u @ W_x (44 cols) ;
//     dt = softplus(b_dt + xd[:12] @ W_dt) ; y_acc init = 4*D*u.
//     y_acc SEPARATE from x_val (halo-race invariant).
// ---------------------------------------------------------------------------
__global__ void k2_conv_dt(const float* __restrict__ x_val,
                           const float* __restrict__ conv_w, const float* __restrict__ conv_b,
                           const float* __restrict__ W_x, const float* __restrict__ W_dt,
                           const float* __restrict__ b_dt, const float* __restrict__ Dp,
                           __half* __restrict__ u_out, float* __restrict__ xd_out,
                           float* __restrict__ dt32, float* __restrict__ y_acc) {
    __shared__ float us[DINNER];
    __shared__ float part[8 * 44];
    __shared__ float xdl[44];
    const int t = threadIdx.x;
    const int pos = blockIdx.x;
    const int b = pos >> 10, hw = pos & 1023, h = hw >> 5, w = hw & 31;

    float acc = conv_b[t];
#pragma unroll
    for (int i = 0; i < 3; ++i) {
        int hh = h + i - 1;
        if (hh < 0 || hh > 31) continue;
#pragma unroll
        for (int j = 0; j < 3; ++j) {
            int ww = w + j - 1;
            if (ww < 0 || ww > 31) continue;
            acc += x_val[((b * 32 + hh) * 32 + ww) * DINNER + t] * conv_w[t * 9 + i * 3 + j];
        }
    }
    float uv = silu_f(acc);
    us[t] = uv;
    u_out[pos * DINNER + t] = __float2half(uv);
    __syncthreads();

    if (t < 352) {
        int o = t % 44, p = t / 44;
        float s = 0.f;
        int j0 = p * 48;
        for (int j = j0; j < j0 + 48; ++j) s += us[j] * W_x[j * 44 + o];
        part[p * 44 + o] = s;
    }
    __syncthreads();
    if (t < 44) {
        float s = 0.f;
#pragma unroll
        for (int p = 0; p < 8; ++p) s += part[p * 44 + t];
        xd_out[pos * 48 + t] = s;
        xdl[t] = s;
    }
    __syncthreads();

    float raw = b_dt[t];
#pragma unroll
    for (int r = 0; r < DTRANK; ++r) raw += xdl[r] * W_dt[r * DINNER + t];
    dt32[pos * DINNER + t] = fmaxf(raw, 0.f) + log1pf(__expf(-fabsf(raw)));

    y_acc[pos * DINNER + t] = 4.f * Dp[t] * uv;
}

// ---------------------------------------------------------------------------
// K3: thread=(d,n), 16-lane butterfly, ballot early exit, batched phases.
//     384 blocks x 256 thr. (round-13 verified)
// ---------------------------------------------------------------------------
__global__ void k3_early(const __half* __restrict__ u, const float* __restrict__ xd,
                         const float* __restrict__ dt32, const float* __restrict__ A_log,
                         float* __restrict__ y_acc) {
    const int t = threadIdx.x;
    const int n = t & 15, dl = t >> 4;
    const int bi = blockIdx.x;
    const int chunk = bi % 24;
    const int b = (bi / 24) % 4;
    const int dir = bi / 96;
    const int d = chunk * 16 + dl;

    const float A = -__expf(A_log[d * DSTATE + n]);

    const __half* ub  = u    + b * SEQL * DINNER;
    const float* xb   = xd   + b * SEQL * 48;
    const float* dtb  = dt32 + b * SEQL * DINNER;
    float* yb = y_acc + b * SEQL * DINNER;

    float cum = 0.f, S = 0.f;
    for (int l0 = 0; l0 < SEQL; l0 += 8) {
        float dtv[8], Bv[8], Cv[8], uv[8];
        int   pk[8];
#pragma unroll
        for (int k = 0; k < 8; ++k) {
            int pos = scan_pos(dir, l0 + k);
            pk[k]  = pos;
            dtv[k] = dtb[pos * DINNER + d];
            Bv[k]  = xb[pos * 48 + DTRANK + n];
            Cv[k]  = xb[pos * 48 + DTRANK + DSTATE + n];
            uv[k]  = __half2float(ub[pos * DINNER + d]);
        }
        float decay[8];
#pragma unroll
        for (int k = 0; k < 8; ++k) { cum += dtv[k] * A; decay[k] = __expf(cum); }
        float rc[8];
#pragma unroll
        for (int k = 0; k < 8; ++k) rc[k] = __builtin_amdgcn_rcpf(decay[k] + 1e-12f);
        float c[8];
#pragma unroll
        for (int k = 0; k < 8; ++k) {
            S += (dtv[k] * Bv[k] * uv[k]) * rc[k];
            c[k] = decay[k] * S * Cv[k];
        }
#pragma unroll
        for (int off = 1; off <= 8; off <<= 1) {
#pragma unroll
            for (int k = 0; k < 8; ++k) c[k] += __shfl_xor(c[k], off);
        }
        if (n == 0) {
#pragma unroll
            for (int k = 0; k < 8; ++k) atomicAdd(&yb[pk[k] * DINNER + d], c[k]);
        }
        if (__ballot(cum > -110.f) == 0ull) break;
    }
}

// ---------------------------------------------------------------------------
// K4: LayerNorm + gate + out-proj. 512 blocks x 384 thr, 8 pos/block.
//     LN: two positions concurrently (half = t/192). GEMM: 8 positions split
//     across the two halves (4 acc/thread), float4 LDS + 4x dd-unroll.
// ---------------------------------------------------------------------------
__global__ void k4_out(const float* __restrict__ y_acc, const float* __restrict__ gz,
                       const float* __restrict__ gamma, const float* __restrict__ beta,
                       const float* __restrict__ W_out, float* __restrict__ out) {
    __shared__ float g_s[8 * DINNER];
    __shared__ float red[12];
    const int t = threadIdx.x;          // 0..383
    const int half = t / 192, tc = t % 192;
    const int lane = t & 63, wv = t >> 6;     // waves 0-2: half0, 3-5: half1
    const int pos0 = blockIdx.x << 3;

    const float g0c = gamma[tc], g1c = gamma[tc + 192];
    const float b0c = beta[tc],  b1c = beta[tc + 192];

    for (int it = 0; it < 4; ++it) {
        int p = it * 2 + half;
        int pos = pos0 + p;
        float y0 = y_acc[pos * DINNER + tc];
        float y1 = y_acc[pos * DINNER + tc + 192];

        float s = y0 + y1;
#pragma unroll
        for (int off = 32; off > 0; off >>= 1) s += __shfl_xor(s, off);
        if (lane == 0) red[wv] = s;
        __syncthreads();
        float mu = (red[half * 3] + red[half * 3 + 1] + red[half * 3 + 2]) * (1.f / 384.f);

        float d0 = y0 - mu, d1 = y1 - mu;
        float sq = d0 * d0 + d1 * d1;
#pragma unroll
        for (int off = 32; off > 0; off >>= 1) sq += __shfl_xor(sq, off);
        if (lane == 0) red[6 + wv] = sq;
        __syncthreads();
        float var = (red[6 + half * 3] + red[6 + half * 3 + 1] + red[6 + half * 3 + 2]) * (1.f / 384.f);
        float inv = rsqrtf(var + 1e-5f);

        g_s[p * DINNER + tc]       = (d0 * inv * g0c + b0c) * gz[pos * DINNER + tc];
        g_s[p * DINNER + tc + 192] = (d1 * inv * g1c + b1c) * gz[pos * DINNER + tc + 192];
    }
    __syncthreads();

    // GEMM: this thread handles col=tc for positions half*4 .. half*4+3
    float acc[4] = {0.f, 0.f, 0.f, 0.f};
    const int pbase = half * 4;
    for (int dd = 0; dd < DINNER; dd += 4) {
        float w0 = W_out[(dd + 0) * DMODEL + tc];
        float w1 = W_out[(dd + 1) * DMODEL + tc];
        float w2 = W_out[(dd + 2) * DMODEL + tc];
        float w3 = W_out[(dd + 3) * DMODEL + tc];
#pragma unroll
        for (int i = 0; i < 4; ++i) {
            const float4 g = *(const float4*)&g_s[(pbase + i) * DINNER + dd];
            acc[i] += g.x * w0 + g.y * w1 + g.z * w2 + g.w * w3;
        }
    }
#pragma unroll
    for (int i = 0; i < 4; ++i) out[(pos0 + pbase + i) * DMODEL + tc] = acc[i];
}

// ---------------------------------------------------------------------------
extern "C" void kernel_launch(void* const* d_in, const int* in_sizes, int n_in,
                              void* d_out, int out_size, void* d_ws, size_t ws_size,
                              hipStream_t stream) {
    (void)in_sizes; (void)n_in; (void)out_size; (void)ws_size;
    const float* x      = (const float*)d_in[0];
    const float* W_in   = (const float*)d_in[1];
    const float* conv_w = (const float*)d_in[2];
    const float* conv_b = (const float*)d_in[3];
    const float* W_x    = (const float*)d_in[4];
    const float* W_dt   = (const float*)d_in[5];
    const float* b_dt   = (const float*)d_in[6];
    const float* A_log  = (const float*)d_in[7];
    const float* Dp     = (const float*)d_in[8];
    const float* W_out  = (const float*)d_in[9];
    const float* gamma  = (const float*)d_in[10];
    const float* beta   = (const float*)d_in[11];

    // ws layout (27.75 MB = 29097984 B, verified available round 9):
    //  x_val fp32 : 6 MB    @ 0
    //  u     fp16 : 3 MB    @ 6291456
    //  xd    fp32 : 0.75 MB @ 9437184
    //  dt32  fp32 : 6 MB    @ 10223616
    //  gz    fp32 : 6 MB    @ 16515072
    //  y_acc fp32 : 6 MB    @ 22806528   (SEPARATE from x_val: no halo race)
    char* base = (char*)d_ws;
    float*  x_val = (float*)base;
    __half* u     = (__half*)(base + 6291456);
    float*  xd    = (float*)(base + 9437184);
    float*  dt32  = (float*)(base + 10223616);
    float*  gz    = (float*)(base + 16515072);
    float*  y_acc = (float*)(base + 22806528);

    hipLaunchKernelGGL(k1_inproj, dim3(NPOS / 8), dim3(768), 0, stream, x, W_in, x_val, gz);
    hipLaunchKernelGGL(k2_conv_dt, dim3(NPOS), dim3(384), 0, stream,
                       x_val, conv_w, conv_b, W_x, W_dt, b_dt, Dp, u, xd, dt32, y_acc);
    hipLaunchKernelGGL(k3_early, dim3(384), dim3(256), 0, stream,
                       u, xd, dt32, A_log, y_acc);
    hipLaunchKernelGGL(k4_out, dim3(NPOS / 8), dim3(384), 0, stream,
                       y_acc, gz, gamma, beta, W_out, (float*)d_out);
}

// Round 15
// 214.767 us; speedup vs baseline: 1.3841x; 1.0142x over previous
//
#include <hip/hip_runtime.h>
#include <hip/hip_fp16.h>

#define DMODEL 192
#define DINNER 384
#define NPOS   4096   // B*H*W = 4*32*32
#define SEQL   1024   // H*W
#define DSTATE 16
#define DTRANK 12

__device__ __forceinline__ float silu_f(float v) { return v * (1.f / (1.f + __expf(-v))); }

__device__ __forceinline__ int scan_pos(int dir, int l) {
    int s = (dir & 1) ? (SEQL - 1 - l) : l;
    return (dir & 2) ? (((s & 31) << 5) | (s >> 5)) : s;
}

// ---------------------------------------------------------------------------
// K1: xz = x @ W_in. NO LDS — x is read with wave-uniform addresses (scalar
//     load path; LDS broadcast at 12cyc/b128 was the round-14 bottleneck).
//     1536 blocks x 256 thr: block = (pos-group of 8) x (col-group of 256).
// ---------------------------------------------------------------------------
__global__ void k1_inproj(const float* __restrict__ x, const float* __restrict__ W_in,
                          float* __restrict__ x_val, float* __restrict__ gz) {
    const int t = threadIdx.x;               // 0..255
    const int bi = blockIdx.x;               // 1536 = 512 posgrp * 3 colgrp
    const int colg = bi % 3;
    const int pos0 = (bi / 3) << 3;
    const int col = colg * 256 + t;          // 0..767

    const float* xr = x + pos0 * DMODEL;     // wave-uniform base

    float acc[8] = {0,0,0,0,0,0,0,0};
    for (int c = 0; c < DMODEL; c += 4) {
        float w0 = W_in[(c + 0) * 768 + col];
        float w1 = W_in[(c + 1) * 768 + col];
        float w2 = W_in[(c + 2) * 768 + col];
        float w3 = W_in[(c + 3) * 768 + col];
#pragma unroll
        for (int g = 0; g < 8; ++g) {
            const float4 xv = *(const float4*)&xr[g * DMODEL + c];   // uniform -> s_load
            acc[g] += xv.x * w0 + xv.y * w1 + xv.z * w2 + xv.w * w3;
        }
    }
    if (col < DINNER) {
#pragma unroll
        for (int g = 0; g < 8; ++g) x_val[(pos0 + g) * DINNER + col] = acc[g];
    } else {
#pragma unroll
        for (int g = 0; g < 8; ++g) gz[(pos0 + g) * DINNER + (col - DINNER)] = silu_f(acc[g]);
    }
}

// ---------------------------------------------------------------------------
// K2: depthwise conv3x3 + bias + silu -> u (fp16) ; xd = u @ W_x (44 cols) ;
//     dt = softplus(b_dt + xd[:12] @ W_dt) ; y_acc init = 4*D*u.
//     y_acc SEPARATE from x_val (halo-race invariant).
// ---------------------------------------------------------------------------
__global__ void k2_conv_dt(const float* __restrict__ x_val,
                           const float* __restrict__ conv_w, const float* __restrict__ conv_b,
                           const float* __restrict__ W_x, const float* __restrict__ W_dt,
                           const float* __restrict__ b_dt, const float* __restrict__ Dp,
                           __half* __restrict__ u_out, float* __restrict__ xd_out,
                           float* __restrict__ dt32, float* __restrict__ y_acc) {
    __shared__ float us[DINNER];
    __shared__ float part[8 * 44];
    __shared__ float xdl[44];
    const int t = threadIdx.x;
    const int pos = blockIdx.x;
    const int b = pos >> 10, hw = pos & 1023, h = hw >> 5, w = hw & 31;

    float acc = conv_b[t];
#pragma unroll
    for (int i = 0; i < 3; ++i) {
        int hh = h + i - 1;
        if (hh < 0 || hh > 31) continue;
#pragma unroll
        for (int j = 0; j < 3; ++j) {
            int ww = w + j - 1;
            if (ww < 0 || ww > 31) continue;
            acc += x_val[((b * 32 + hh) * 32 + ww) * DINNER + t] * conv_w[t * 9 + i * 3 + j];
        }
    }
    float uv = silu_f(acc);
    us[t] = uv;
    u_out[pos * DINNER + t] = __float2half(uv);
    __syncthreads();

    if (t < 352) {
        int o = t % 44, p = t / 44;
        float s = 0.f;
        int j0 = p * 48;
        for (int j = j0; j < j0 + 48; ++j) s += us[j] * W_x[j * 44 + o];
        part[p * 44 + o] = s;
    }
    __syncthreads();
    if (t < 44) {
        float s = 0.f;
#pragma unroll
        for (int p = 0; p < 8; ++p) s += part[p * 44 + t];
        xd_out[pos * 48 + t] = s;
        xdl[t] = s;
    }
    __syncthreads();

    float raw = b_dt[t];
#pragma unroll
    for (int r = 0; r < DTRANK; ++r) raw += xdl[r] * W_dt[r * DINNER + t];
    dt32[pos * DINNER + t] = fmaxf(raw, 0.f) + log1pf(__expf(-fabsf(raw)));

    y_acc[pos * DINNER + t] = 4.f * Dp[t] * uv;
}

// ---------------------------------------------------------------------------
// K3: batched-phase scan with 2-buffer software-pipelined prefetch across the
//     ballot break (round-14 version lost a full L2 round-trip per chunk).
//     Arithmetic & reduction order identical. 384 blocks x 256 thr.
// ---------------------------------------------------------------------------
__device__ __forceinline__ void k3_load(const float* __restrict__ dtb,
                                        const float* __restrict__ xb,
                                        const __half* __restrict__ ub,
                                        int dir, int l0, int d, int n,
                                        float* dtv, float* Bv, float* Cv, float* uv, int* pk) {
#pragma unroll
    for (int k = 0; k < 8; ++k) {
        int pos = scan_pos(dir, l0 + k);
        pk[k]  = pos;
        dtv[k] = dtb[pos * DINNER + d];
        Bv[k]  = xb[pos * 48 + DTRANK + n];
        Cv[k]  = xb[pos * 48 + DTRANK + DSTATE + n];
        uv[k]  = __half2float(ub[pos * DINNER + d]);
    }
}

__device__ __forceinline__ bool k3_compute(float A, float& cum, float& S,
                                           const float* dtv, const float* Bv,
                                           const float* Cv, const float* uv, const int* pk,
                                           float* __restrict__ yb, int d, int n) {
    float decay[8];
#pragma unroll
    for (int k = 0; k < 8; ++k) { cum += dtv[k] * A; decay[k] = __expf(cum); }
    float rc[8];
#pragma unroll
    for (int k = 0; k < 8; ++k) rc[k] = __builtin_amdgcn_rcpf(decay[k] + 1e-12f);
    float c[8];
#pragma unroll
    for (int k = 0; k < 8; ++k) {
        S += (dtv[k] * Bv[k] * uv[k]) * rc[k];
        c[k] = decay[k] * S * Cv[k];
    }
#pragma unroll
    for (int off = 1; off <= 8; off <<= 1) {
#pragma unroll
        for (int k = 0; k < 8; ++k) c[k] += __shfl_xor(c[k], off);
    }
    if (n == 0) {
#pragma unroll
        for (int k = 0; k < 8; ++k) atomicAdd(&yb[pk[k] * DINNER + d], c[k]);
    }
    return __ballot(cum > -110.f) != 0ull;       // alive?
}

__global__ void k3_early(const __half* __restrict__ u, const float* __restrict__ xd,
                         const float* __restrict__ dt32, const float* __restrict__ A_log,
                         float* __restrict__ y_acc) {
    const int t = threadIdx.x;
    const int n = t & 15, dl = t >> 4;
    const int bi = blockIdx.x;
    const int chunk = bi % 24;
    const int b = (bi / 24) % 4;
    const int dir = bi / 96;
    const int d = chunk * 16 + dl;

    const float A = -__expf(A_log[d * DSTATE + n]);

    const __half* ub  = u    + b * SEQL * DINNER;
    const float* xb   = xd   + b * SEQL * 48;
    const float* dtb  = dt32 + b * SEQL * DINNER;
    float* yb = y_acc + b * SEQL * DINNER;

    float dtvA[8], BvA[8], CvA[8], uvA[8]; int pkA[8];
    float dtvB[8], BvB[8], CvB[8], uvB[8]; int pkB[8];

    float cum = 0.f, S = 0.f;
    k3_load(dtb, xb, ub, dir, 0, d, n, dtvA, BvA, CvA, uvA, pkA);
    for (int l0 = 0; l0 < SEQL; l0 += 16) {
        // prefetch chunk l0+8 (always in range: l0 <= 1008)
        k3_load(dtb, xb, ub, dir, l0 + 8, d, n, dtvB, BvB, CvB, uvB, pkB);
        if (!k3_compute(A, cum, S, dtvA, BvA, CvA, uvA, pkA, yb, d, n)) break;
        // prefetch chunk l0+16 (redundant reload at the tail; harmless)
        int ln = (l0 + 16 < SEQL) ? (l0 + 16) : (l0 + 8);
        k3_load(dtb, xb, ub, dir, ln, d, n, dtvA, BvA, CvA, uvA, pkA);
        if (!k3_compute(A, cum, S, dtvB, BvB, CvB, uvB, pkB, yb, d, n)) break;
    }
}

// ---------------------------------------------------------------------------
// K4: LayerNorm + gate + out-proj. 512 blocks x 384 thr, 8 pos/block.
//     (round-14 verified)
// ---------------------------------------------------------------------------
__global__ void k4_out(const float* __restrict__ y_acc, const float* __restrict__ gz,
                       const float* __restrict__ gamma, const float* __restrict__ beta,
                       const float* __restrict__ W_out, float* __restrict__ out) {
    __shared__ float g_s[8 * DINNER];
    __shared__ float red[12];
    const int t = threadIdx.x;          // 0..383
    const int half = t / 192, tc = t % 192;
    const int lane = t & 63, wv = t >> 6;
    const int pos0 = blockIdx.x << 3;

    const float g0c = gamma[tc], g1c = gamma[tc + 192];
    const float b0c = beta[tc],  b1c = beta[tc + 192];

    for (int it = 0; it < 4; ++it) {
        int p = it * 2 + half;
        int pos = pos0 + p;
        float y0 = y_acc[pos * DINNER + tc];
        float y1 = y_acc[pos * DINNER + tc + 192];

        float s = y0 + y1;
#pragma unroll
        for (int off = 32; off > 0; off >>= 1) s += __shfl_xor(s, off);
        if (lane == 0) red[wv] = s;
        __syncthreads();
        float mu = (red[half * 3] + red[half * 3 + 1] + red[half * 3 + 2]) * (1.f / 384.f);

        float d0 = y0 - mu, d1 = y1 - mu;
        float sq = d0 * d0 + d1 * d1;
#pragma unroll
        for (int off = 32; off > 0; off >>= 1) sq += __shfl_xor(sq, off);
        if (lane == 0) red[6 + wv] = sq;
        __syncthreads();
        float var = (red[6 + half * 3] + red[6 + half * 3 + 1] + red[6 + half * 3 + 2]) * (1.f / 384.f);
        float inv = rsqrtf(var + 1e-5f);

        g_s[p * DINNER + tc]       = (d0 * inv * g0c + b0c) * gz[pos * DINNER + tc];
        g_s[p * DINNER + tc + 192] = (d1 * inv * g1c + b1c) * gz[pos * DINNER + tc + 192];
    }
    __syncthreads();

    float acc[4] = {0.f, 0.f, 0.f, 0.f};
    const int pbase = half * 4;
    for (int dd = 0; dd < DINNER; dd += 4) {
        float w0 = W_out[(dd + 0) * DMODEL + tc];
        float w1 = W_out[(dd + 1) * DMODEL + tc];
        float w2 = W_out[(dd + 2) * DMODEL + tc];
        float w3 = W_out[(dd + 3) * DMODEL + tc];
#pragma unroll
        for (int i = 0; i < 4; ++i) {
            const float4 g = *(const float4*)&g_s[(pbase + i) * DINNER + dd];
            acc[i] += g.x * w0 + g.y * w1 + g.z * w2 + g.w * w3;
        }
    }
#pragma unroll
    for (int i = 0; i < 4; ++i) out[(pos0 + pbase + i) * DMODEL + tc] = acc[i];
}

// ---------------------------------------------------------------------------
extern "C" void kernel_launch(void* const* d_in, const int* in_sizes, int n_in,
                              void* d_out, int out_size, void* d_ws, size_t ws_size,
                              hipStream_t stream) {
    (void)in_sizes; (void)n_in; (void)out_size; (void)ws_size;
    const float* x      = (const float*)d_in[0];
    const float* W_in   = (const float*)d_in[1];
    const float* conv_w = (const float*)d_in[2];
    const float* conv_b = (const float*)d_in[3];
    const float* W_x    = (const float*)d_in[4];
    const float* W_dt   = (const float*)d_in[5];
    const float* b_dt   = (const float*)d_in[6];
    const float* A_log  = (const float*)d_in[7];
    const float* Dp     = (const float*)d_in[8];
    const float* W_out  = (const float*)d_in[9];
    const float* gamma  = (const float*)d_in[10];
    const float* beta   = (const float*)d_in[11];

    // ws layout (27.75 MB = 29097984 B, verified available):
    //  x_val fp32 : 6 MB    @ 0
    //  u     fp16 : 3 MB    @ 6291456
    //  xd    fp32 : 0.75 MB @ 9437184
    //  dt32  fp32 : 6 MB    @ 10223616
    //  gz    fp32 : 6 MB    @ 16515072
    //  y_acc fp32 : 6 MB    @ 22806528   (SEPARATE from x_val: no halo race)
    char* base = (char*)d_ws;
    float*  x_val = (float*)base;
    __half* u     = (__half*)(base + 6291456);
    float*  xd    = (float*)(base + 9437184);
    float*  dt32  = (float*)(base + 10223616);
    float*  gz    = (float*)(base + 16515072);
    float*  y_acc = (float*)(base + 22806528);

    hipLaunchKernelGGL(k1_inproj, dim3(NPOS / 8 * 3), dim3(256), 0, stream, x, W_in, x_val, gz);
    hipLaunchKernelGGL(k2_conv_dt, dim3(NPOS), dim3(384), 0, stream,
                       x_val, conv_w, conv_b, W_x, W_dt, b_dt, Dp, u, xd, dt32, y_acc);
    hipLaunchKernelGGL(k3_early, dim3(384), dim3(256), 0, stream,
                       u, xd, dt32, A_log, y_acc);
    hipLaunchKernelGGL(k4_out, dim3(NPOS / 8), dim3(384), 0, stream,
                       y_acc, gz, gamma, beta, W_out, (float*)d_out);
}